// Round 5
// baseline (1198.156 us; speedup 1.0000x reference)
//
#include <hip/hip_runtime.h>
#include <stdint.h>

#define EPS 1e-5f

typedef __attribute__((ext_vector_type(8))) short bf16x8;
typedef __attribute__((ext_vector_type(4))) float f32x4;

__device__ __forceinline__ short f2bf(float f) {
  union { float f; unsigned u; } c; c.f = f;
  unsigned r = (c.u + 0x7FFFu + ((c.u >> 16) & 1u)) >> 16;
  return (short)r;
}
__device__ __forceinline__ float bf2f(unsigned short s) {
  union { unsigned u; float f; } c; c.u = ((unsigned)s) << 16;
  return c.f;
}

// async 16B global->LDS copy (linear dest = wave-uniform base + lane*16)
#define ASYNC_COPY16(gsrc, ldst)                                                   \
  __builtin_amdgcn_global_load_lds(                                                \
      (const __attribute__((address_space(1))) void*)(gsrc),                       \
      (__attribute__((address_space(3))) void*)(ldst), 16, 0, 0)

// ws float-offset layout (header)
#define WS_SUM1 0
#define WS_SQ1  256
#define WS_SUM2 512
#define WS_SQ2  576
#define WS_M1   640
#define WS_I1   896
#define WS_M2   1152
#define WS_I2   1216
#define H2S_BYTE_OFF 8192

__global__ void k_zero(float* ws) {
  for (int i = threadIdx.x; i < 640; i += 256) ws[i] = 0.f;
}

__global__ void k_finalize(float* ws, int n, int so, int qo, int mo, int io, float invE) {
  int j = threadIdx.x;
  if (j < n) {
    float m = ws[so + j] * invE;
    float var = ws[qo + j] * invE - m * m;
    ws[mo + j] = m;
    ws[io + j] = rsqrtf(var + EPS);
  }
}

// MODE 0: GEMM1 -> stats1 (XT=1: also dump swizzled bf16 A-tile image to f12s).
// MODE 1: GEMM1+norm+GEMM2 -> stats2 + h2 store (XT=1: stage A from f12s via global_load_lds).
// MODE 2: full recompute -> out (fallback when ws too small for h2 store).
// LDS (MODE>=1): A image [0,16K) aliased under g [0,32K); outp at 32768 (MODE 2).
template <int MODE, int XT>
__global__ __launch_bounds__(256, 4) void fused_pass(
    const float* __restrict__ emb, const int* __restrict__ ei,
    const float* __restrict__ W1, const float* __restrict__ b1,
    const float* __restrict__ W2, const float* __restrict__ b2,
    const float* __restrict__ W3, const float* __restrict__ b3,
    float* __restrict__ ws, unsigned short* __restrict__ h2s,
    char* __restrict__ f12s, float* __restrict__ out, int E, int storeH2) {
  extern __shared__ __align__(16) char lds[];
  const int tid = threadIdx.x;
  const int lane = tid & 63;
  const int w = tid >> 6;   // wave 0..3
  const int l15 = lane & 15;
  const int l4 = lane >> 4; // 0..3

  // ---- persistent B1 fragments: wave w owns h1 columns [64w, 64w+64)
  bf16x8 B1[4][4]; // [ni][kk]
#pragma unroll
  for (int ni = 0; ni < 4; ++ni)
#pragma unroll
    for (int kk = 0; kk < 4; ++kk) {
      const int c = w * 64 + ni * 16 + l15;
      const int kb = kk * 32 + l4 * 8;
      bf16x8 v;
#pragma unroll
      for (int i = 0; i < 8; ++i) v[i] = f2bf(W1[(kb + i) * 256 + c]);
      B1[ni][kk] = v;
    }
  float b1v[4], m1v[4] = {0, 0, 0, 0}, i1v[4] = {0, 0, 0, 0};
#pragma unroll
  for (int ni = 0; ni < 4; ++ni) {
    const int c = w * 64 + ni * 16 + l15;
    b1v[ni] = b1[c];
    if (MODE >= 1) { m1v[ni] = ws[WS_M1 + c]; i1v[ni] = ws[WS_I1 + c]; }
  }
  bf16x8 B2[8];
  float b2v = 0.f, m2v = 0.f, i2v = 0.f, w3v = 0.f;
  if (MODE >= 1) {
#pragma unroll
    for (int kk = 0; kk < 8; ++kk) {
      const int c = w * 16 + l15;
      const int kb = kk * 32 + l4 * 8;
      bf16x8 v;
#pragma unroll
      for (int i = 0; i < 8; ++i) v[i] = f2bf(W2[(kb + i) * 64 + c]);
      B2[kk] = v;
    }
    b2v = b2[w * 16 + l15];
    if (MODE == 2) {
      m2v = ws[WS_M2 + w * 16 + l15];
      i2v = ws[WS_I2 + w * 16 + l15];
      w3v = W3[w * 16 + l15];
    }
  }

  float sAcc[4] = {0, 0, 0, 0}, qAcc[4] = {0, 0, 0, 0}; // MODE0 stats1
  float s2A = 0.f, q2A = 0.f;                           // MODE1 stats2

  const int nTiles = E >> 6;
  for (int t = blockIdx.x; t < nTiles; t += gridDim.x) {
    const int e0 = t << 6;
    __syncthreads(); // prev iteration's A/g/outp readers done before restage

    // ---- stage A tile image [64 edges][128 cols] bf16, XOR-swizzled
    if (MODE == 1 && XT == 1) {
      // linear async copy from pre-swizzled f12 image
      const char* src = f12s + (size_t)t * 16384 + w * 4096 + lane * 16;
      char* dst = lds + w * 4096;
#pragma unroll
      for (int r = 0; r < 4; ++r)
        ASYNC_COPY16(src + r * 1024, dst + r * 1024);
    } else {
      const int e = tid >> 2, q = tid & 3;
      const int nidx = (q < 2) ? ei[e0 + e] : ei[E + e0 + e];
      const float* src = emb + (long)nidx * 64 + (q & 1) * 32;
#pragma unroll
      for (int jj = 0; jj < 4; ++jj) {
        float4 fa = *reinterpret_cast<const float4*>(src + jj * 8);
        float4 fb = *reinterpret_cast<const float4*>(src + jj * 8 + 4);
        bf16x8 p;
        p[0] = f2bf(fa.x); p[1] = f2bf(fa.y); p[2] = f2bf(fa.z); p[3] = f2bf(fa.w);
        p[4] = f2bf(fb.x); p[5] = f2bf(fb.y); p[6] = f2bf(fb.z); p[7] = f2bf(fb.w);
        int byte = e * 256 + q * 64 + jj * 16;
        byte ^= (e & 7) << 4;
        *reinterpret_cast<bf16x8*>(lds + byte) = p;
      }
    }
    if (MODE == 2) {
      if (tid < 64) reinterpret_cast<float*>(lds + 32768)[tid] = 0.f;
    }
    __syncthreads(); // (drains vmcnt for global_load_lds per __syncthreads semantics)

    // ---- MODE0 XT1: dump the tile image to f12s (coalesced, full lines)
    if (MODE == 0 && XT == 1) {
      const char* srcL = lds + w * 4096;
      char* dstG = f12s + (size_t)t * 16384 + w * 4096;
#pragma unroll
      for (int r = 0; r < 4; ++r) {
        const bf16x8 v = *reinterpret_cast<const bf16x8*>(srcL + r * 1024 + lane * 16);
        *reinterpret_cast<bf16x8*>(dstG + r * 1024 + lane * 16) = v;
      }
    }

    // ---- GEMM1: wave tile 64 rows x 64 cols
    f32x4 acc[4][4];
#pragma unroll
    for (int mi = 0; mi < 4; ++mi)
#pragma unroll
      for (int ni = 0; ni < 4; ++ni) acc[mi][ni] = f32x4{0.f, 0.f, 0.f, 0.f};
#pragma unroll
    for (int kk = 0; kk < 4; ++kk) {
      bf16x8 af[4];
#pragma unroll
      for (int mi = 0; mi < 4; ++mi) {
        const int row = mi * 16 + l15;
        int byte = row * 256 + kk * 64 + l4 * 16;
        byte ^= (row & 7) << 4;
        af[mi] = *reinterpret_cast<const bf16x8*>(lds + byte);
      }
#pragma unroll
      for (int ni = 0; ni < 4; ++ni)
#pragma unroll
        for (int mi = 0; mi < 4; ++mi)
          acc[mi][ni] = __builtin_amdgcn_mfma_f32_16x16x32_bf16(af[mi], B1[ni][kk], acc[mi][ni], 0, 0, 0);
    }

    if (MODE == 0) {
#pragma unroll
      for (int mi = 0; mi < 4; ++mi)
#pragma unroll
        for (int ni = 0; ni < 4; ++ni)
#pragma unroll
          for (int r = 0; r < 4; ++r) {
            const float v = acc[mi][ni][r] + b1v[ni];
            sAcc[ni] += v;
            qAcc[ni] += v * v;
          }
    } else {
      __syncthreads(); // all GEMM1 A-reads done before g overwrites [0,32K)

      // ---- normalize + relu -> g tile (bf16, swizzled, aliases A)
      char* g = lds;
#pragma unroll
      for (int mi = 0; mi < 4; ++mi)
#pragma unroll
        for (int ni = 0; ni < 4; ++ni) {
          const int c = w * 64 + ni * 16 + l15;
#pragma unroll
          for (int r = 0; r < 4; ++r) {
            const int row = mi * 16 + l4 * 4 + r;
            float v = (acc[mi][ni][r] + b1v[ni] - m1v[ni]) * i1v[ni];
            v = v > 0.f ? v : 0.f;
            int byte = row * 512 + c * 2;
            byte ^= (row & 7) << 4;
            *reinterpret_cast<short*>(g + byte) = f2bf(v);
          }
        }
      __syncthreads();

      // ---- GEMM2: wave tile 64 rows x 16 cols, K=256
      f32x4 acc2[4];
#pragma unroll
      for (int mi = 0; mi < 4; ++mi) acc2[mi] = f32x4{0.f, 0.f, 0.f, 0.f};
#pragma unroll
      for (int kk = 0; kk < 8; ++kk) {
#pragma unroll
        for (int mi = 0; mi < 4; ++mi) {
          const int row = mi * 16 + l15;
          int byte = row * 512 + kk * 64 + l4 * 16;
          byte ^= (row & 7) << 4;
          const bf16x8 a2 = *reinterpret_cast<const bf16x8*>(g + byte);
          acc2[mi] = __builtin_amdgcn_mfma_f32_16x16x32_bf16(a2, B2[kk], acc2[mi], 0, 0, 0);
        }
      }

      if (MODE == 1) {
#pragma unroll
        for (int mi = 0; mi < 4; ++mi)
#pragma unroll
          for (int r = 0; r < 4; ++r) {
            const float v = acc2[mi][r] + b2v;
            s2A += v;
            q2A += v * v;
            if (storeH2) {
              const int row = e0 + mi * 16 + l4 * 4 + r;
              h2s[(size_t)row * 64 + w * 16 + l15] = (unsigned short)f2bf(v);
            }
          }
      } else { // MODE 2: final output
        float* outp = reinterpret_cast<float*>(lds + 32768);
#pragma unroll
        for (int mi = 0; mi < 4; ++mi)
#pragma unroll
          for (int r = 0; r < 4; ++r) {
            const float v = acc2[mi][r] + b2v;
            float z = (v - m2v) * i2v;
            z = z > 0.f ? z : 0.f;
            float pv = z * w3v;
            pv += __shfl_xor(pv, 1);
            pv += __shfl_xor(pv, 2);
            pv += __shfl_xor(pv, 4);
            pv += __shfl_xor(pv, 8);
            if (l15 == 0) atomicAdd(&outp[mi * 16 + l4 * 4 + r], pv);
          }
        __syncthreads();
        if (tid < 64) out[e0 + tid] = outp[tid] + b3[0];
      }
    }
  }

  // ---- flush stats
  if (MODE == 0) {
#pragma unroll
    for (int ni = 0; ni < 4; ++ni) {
      float s = sAcc[ni], q = qAcc[ni];
      s += __shfl_xor(s, 16); s += __shfl_xor(s, 32);
      q += __shfl_xor(q, 16); q += __shfl_xor(q, 32);
      if (lane < 16) {
        atomicAdd(&ws[WS_SUM1 + w * 64 + ni * 16 + lane], s);
        atomicAdd(&ws[WS_SQ1 + w * 64 + ni * 16 + lane], q);
      }
    }
  }
  if (MODE == 1) {
    float s = s2A, q = q2A;
    s += __shfl_xor(s, 16); s += __shfl_xor(s, 32);
    q += __shfl_xor(q, 16); q += __shfl_xor(q, 32);
    if (lane < 16) {
      atomicAdd(&ws[WS_SUM2 + w * 16 + lane], s);
      atomicAdd(&ws[WS_SQ2 + w * 16 + lane], q);
    }
  }
}

// epilogue from stored h2 (bf16): norm2 + relu + dot(W3) + b3
__global__ void k_out(const unsigned short* __restrict__ h2s, const float* __restrict__ ws,
                      const float* __restrict__ W3, const float* __restrict__ b3,
                      float* __restrict__ out, int E) {
  __shared__ float sm[64], si[64], sw[64];
  const int tid = threadIdx.x;
  if (tid < 64) {
    sm[tid] = ws[WS_M2 + tid];
    si[tid] = ws[WS_I2 + tid];
    sw[tid] = W3[tid];
  }
  __syncthreads();
  const int e = blockIdx.x * 256 + tid;
  if (e >= E) return;
  const unsigned short* rp = h2s + (size_t)e * 64;
  float a = 0.f;
#pragma unroll
  for (int jj = 0; jj < 8; ++jj) {
    const bf16x8 v8 = *reinterpret_cast<const bf16x8*>(rp + jj * 8);
#pragma unroll
    for (int i = 0; i < 8; ++i) {
      const int j = jj * 8 + i;
      const float v = bf2f((unsigned short)v8[i]);
      float z = (v - sm[j]) * si[j];
      z = z > 0.f ? z : 0.f;
      a += z * sw[j];
    }
  }
  out[e] = a + b3[0];
}

extern "C" void kernel_launch(void* const* d_in, const int* in_sizes, int n_in,
                              void* d_out, int out_size, void* d_ws, size_t ws_size,
                              hipStream_t stream) {
  (void)n_in; (void)out_size;
  const float* emb = (const float*)d_in[0];
  const int* ei = (const int*)d_in[1];
  const float* W1 = (const float*)d_in[2];
  const float* b1 = (const float*)d_in[3];
  const float* W2 = (const float*)d_in[4];
  const float* b2 = (const float*)d_in[5];
  const float* W3 = (const float*)d_in[6];
  const float* b3 = (const float*)d_in[7];
  float* out = (float*)d_out;
  float* ws = (float*)d_ws;
  unsigned short* h2s = (unsigned short*)((char*)d_ws + H2S_BYTE_OFF);

  const int E = in_sizes[1] / 2;
  const size_t h2bytes = (size_t)E * 64 * 2;    // 102.4 MB
  const size_t f12bytes = (size_t)E * 128 * 2;  // 204.8 MB
  char* f12s = (char*)d_ws + H2S_BYTE_OFF + h2bytes;
  const int storeH2 = (ws_size >= (size_t)H2S_BYTE_OFF + h2bytes) ? 1 : 0;
  const int storeF12 = (ws_size >= (size_t)H2S_BYTE_OFF + h2bytes + f12bytes) ? 1 : 0;
  const float invE = 1.0f / (float)E;

  k_zero<<<1, 256, 0, stream>>>(ws);
  if (storeF12)
    fused_pass<0, 1><<<1024, 256, 16384, stream>>>(emb, ei, W1, b1, W2, b2, W3, b3, ws, h2s, f12s, out, E, storeH2);
  else
    fused_pass<0, 0><<<1024, 256, 16384, stream>>>(emb, ei, W1, b1, W2, b2, W3, b3, ws, h2s, f12s, out, E, storeH2);
  k_finalize<<<1, 256, 0, stream>>>(ws, 256, WS_SUM1, WS_SQ1, WS_M1, WS_I1, invE);
  if (storeF12)
    fused_pass<1, 1><<<1024, 256, 32768, stream>>>(emb, ei, W1, b1, W2, b2, W3, b3, ws, h2s, f12s, out, E, storeH2);
  else
    fused_pass<1, 0><<<1024, 256, 32768, stream>>>(emb, ei, W1, b1, W2, b2, W3, b3, ws, h2s, f12s, out, E, storeH2);
  k_finalize<<<1, 256, 0, stream>>>(ws, 64, WS_SUM2, WS_SQ2, WS_M2, WS_I2, invE);
  if (storeH2)
    k_out<<<(E + 255) / 256, 256, 0, stream>>>(h2s, ws, W3, b3, out, E);
  else
    fused_pass<2, 0><<<1024, 256, 33024, stream>>>(emb, ei, W1, b1, W2, b2, W3, b3, ws, h2s, f12s, out, E, storeH2);
}

// Round 6
// 843.962 us; speedup vs baseline: 1.4197x; 1.4197x over previous
//
#include <hip/hip_runtime.h>
#include <stdint.h>

#define EPS 1e-5f

typedef __attribute__((ext_vector_type(8))) short bf16x8;
typedef __attribute__((ext_vector_type(4))) float f32x4;

__device__ __forceinline__ short f2bf(float f) {
  union { float f; unsigned u; } c; c.f = f;
  unsigned r = (c.u + 0x7FFFu + ((c.u >> 16) & 1u)) >> 16;
  return (short)r;
}
__device__ __forceinline__ float bf2f(unsigned short s) {
  union { unsigned u; float f; } c; c.u = ((unsigned)s) << 16;
  return c.f;
}

// async 16B global->LDS copy (linear dest = wave-uniform base + lane*16)
#define ASYNC_COPY16(gsrc, ldst)                                                   \
  __builtin_amdgcn_global_load_lds(                                                \
      (const __attribute__((address_space(1))) void*)(gsrc),                       \
      (__attribute__((address_space(3))) void*)(ldst), 16, 0, 0)

// ws float-offset layout (header)
#define WS_SUM1 0
#define WS_SQ1  256
#define WS_SUM2 512
#define WS_SQ2  576
#define WS_M1   640
#define WS_I1   896
#define WS_M2   1152
#define WS_I2   1216
#define H2S_BYTE_OFF 8192

__global__ void k_zero(float* ws) {
  for (int i = threadIdx.x; i < 640; i += 256) ws[i] = 0.f;
}

__global__ void k_finalize(float* ws, int n, int so, int qo, int mo, int io, float invE) {
  int j = threadIdx.x;
  if (j < n) {
    float m = ws[so + j] * invE;
    float var = ws[qo + j] * invE - m * m;
    ws[mo + j] = m;
    ws[io + j] = rsqrtf(var + EPS);
  }
}

// ============ PASS A: gather + GEMM1 + stats1 + h1-image dump ============
// LDS: A tile [64][128] bf16 swizzled at [0,16384); h1 image [16384,49152).
// launch_bounds(256,2): B1(64)+acc(64)+pf(32)+misc must NOT spill (round-5 lesson:
// (256,4) forced 64 VGPRs -> B1/B2 spilled to scratch -> FETCH 1.6GB, 857us).
__global__ __launch_bounds__(256, 2) void k_pass_a(
    const float* __restrict__ emb, const int* __restrict__ ei,
    const float* __restrict__ W1, const float* __restrict__ b1,
    float* __restrict__ ws, char* __restrict__ h1img, int E) {
  extern __shared__ __align__(16) char lds[];
  const int tid = threadIdx.x;
  const int lane = tid & 63;
  const int w = tid >> 6;
  const int l15 = lane & 15;
  const int l4 = lane >> 4;

  bf16x8 B1[4][4]; // [ni][kk]; wave w owns h1 cols [64w,64w+64)
#pragma unroll
  for (int ni = 0; ni < 4; ++ni)
#pragma unroll
    for (int kk = 0; kk < 4; ++kk) {
      const int c = w * 64 + ni * 16 + l15;
      const int kb = kk * 32 + l4 * 8;
      bf16x8 v;
#pragma unroll
      for (int i = 0; i < 8; ++i) v[i] = f2bf(W1[(kb + i) * 256 + c]);
      B1[ni][kk] = v;
    }
  float b1v[4];
#pragma unroll
  for (int ni = 0; ni < 4; ++ni) b1v[ni] = b1[w * 64 + ni * 16 + l15];

  float sAcc[4] = {0, 0, 0, 0}, qAcc[4] = {0, 0, 0, 0};

  const int nTiles = E >> 6;
  const int e_ = tid >> 2, q_ = tid & 3; // staging role: edge e_, 32-col chunk q_

  // prefetch registers for tile t (T14 issue-early: in flight across GEMM1)
  float4 pf[8];
  {
    const int e0 = blockIdx.x << 6;
    const int nidx = (q_ < 2) ? ei[e0 + e_] : ei[E + e0 + e_];
    const float* src = emb + (long)nidx * 64 + (q_ & 1) * 32;
#pragma unroll
    for (int jj = 0; jj < 8; ++jj)
      pf[jj] = *reinterpret_cast<const float4*>(src + jj * 4);
  }

  for (int t = blockIdx.x; t < nTiles; t += gridDim.x) {
    // ---- write prefetched regs -> A tile (swizzled bf16)
#pragma unroll
    for (int jj = 0; jj < 4; ++jj) {
      bf16x8 p;
      p[0] = f2bf(pf[2 * jj].x); p[1] = f2bf(pf[2 * jj].y);
      p[2] = f2bf(pf[2 * jj].z); p[3] = f2bf(pf[2 * jj].w);
      p[4] = f2bf(pf[2 * jj + 1].x); p[5] = f2bf(pf[2 * jj + 1].y);
      p[6] = f2bf(pf[2 * jj + 1].z); p[7] = f2bf(pf[2 * jj + 1].w);
      int byte = e_ * 256 + q_ * 64 + jj * 16;
      byte ^= (e_ & 7) << 4;
      *reinterpret_cast<bf16x8*>(lds + byte) = p;
    }
    __syncthreads(); // sync#1: A tile ready

    // ---- issue next tile's gather (consumed at next loop-top; latency hidden)
    {
      const int tn = t + (int)gridDim.x;
      const int tv = (tn < nTiles) ? tn : t;
      const int e0n = tv << 6;
      const int nidx = (q_ < 2) ? ei[e0n + e_] : ei[E + e0n + e_];
      const float* src = emb + (long)nidx * 64 + (q_ & 1) * 32;
#pragma unroll
      for (int jj = 0; jj < 8; ++jj)
        pf[jj] = *reinterpret_cast<const float4*>(src + jj * 4);
    }

    // ---- GEMM1: wave tile 64 rows x 64 cols, K=128
    f32x4 acc[4][4];
#pragma unroll
    for (int mi = 0; mi < 4; ++mi)
#pragma unroll
      for (int ni = 0; ni < 4; ++ni) acc[mi][ni] = f32x4{0.f, 0.f, 0.f, 0.f};
#pragma unroll
    for (int kk = 0; kk < 4; ++kk) {
      bf16x8 af[4];
#pragma unroll
      for (int mi = 0; mi < 4; ++mi) {
        const int row = mi * 16 + l15;
        int byte = row * 256 + kk * 64 + l4 * 16;
        byte ^= (row & 7) << 4;
        af[mi] = *reinterpret_cast<const bf16x8*>(lds + byte);
      }
#pragma unroll
      for (int ni = 0; ni < 4; ++ni)
#pragma unroll
        for (int mi = 0; mi < 4; ++mi)
          acc[mi][ni] = __builtin_amdgcn_mfma_f32_16x16x32_bf16(af[mi], B1[ni][kk], acc[mi][ni], 0, 0, 0);
    }

    // ---- stats1 (on bf16-rounded values, matching what pass B reads) + h1 image
    char* g = lds + 16384;
#pragma unroll
    for (int mi = 0; mi < 4; ++mi)
#pragma unroll
      for (int ni = 0; ni < 4; ++ni) {
        const int c = w * 64 + ni * 16 + l15;
#pragma unroll
        for (int r = 0; r < 4; ++r) {
          const int row = mi * 16 + l4 * 4 + r;
          const short vb = f2bf(acc[mi][ni][r] + b1v[ni]);
          const float vr = bf2f((unsigned short)vb);
          sAcc[ni] += vr;
          qAcc[ni] += vr * vr;
          int byte = row * 512 + c * 2;
          byte ^= (row & 7) << 4;
          *reinterpret_cast<short*>(g + byte) = vb;
        }
      }
    __syncthreads(); // sync#2: image complete (also orders A-write of next iter)

    // ---- dump h1 image, coalesced full lines, nontemporal (don't thrash L2/L3)
    {
      const char* srcL = lds + 16384 + w * 8192;
      char* dstG = h1img + (size_t)t * 32768 + w * 8192;
#pragma unroll
      for (int r = 0; r < 8; ++r) {
        const bf16x8 v = *reinterpret_cast<const bf16x8*>(srcL + r * 1024 + lane * 16);
        __builtin_nontemporal_store(v, reinterpret_cast<bf16x8*>(dstG + r * 1024 + lane * 16));
      }
    }
    // no extra sync: next iter's g-writes are ordered after next sync#1.
  }

  // ---- flush stats1
#pragma unroll
  for (int ni = 0; ni < 4; ++ni) {
    float s = sAcc[ni], q = qAcc[ni];
    s += __shfl_xor(s, 16); s += __shfl_xor(s, 32);
    q += __shfl_xor(q, 16); q += __shfl_xor(q, 32);
    if (lane < 16) {
      atomicAdd(&ws[WS_SUM1 + w * 64 + ni * 16 + lane], s);
      atomicAdd(&ws[WS_SQ1 + w * 64 + ni * 16 + lane], q);
    }
  }
}

// ============ PASS B: h1 image -> norm1+ReLU (in-reg) -> GEMM2 -> stats2 + h2 ============
// LDS: img [0,32768) (bounce aliases [0,8192)); m1 [32768,33792); i1 [33792,34816).
__global__ __launch_bounds__(256, 4) void k_pass_b(
    const char* __restrict__ h1img, const float* __restrict__ W2,
    const float* __restrict__ b2, float* __restrict__ ws,
    unsigned short* __restrict__ h2s, int E) {
  extern __shared__ __align__(16) char lds[];
  const int tid = threadIdx.x;
  const int lane = tid & 63;
  const int w = tid >> 6;
  const int l15 = lane & 15;
  const int l4 = lane >> 4;

  bf16x8 B2[8]; // wave w owns h2 cols [16w,16w+16)
#pragma unroll
  for (int kk = 0; kk < 8; ++kk) {
    const int c = w * 16 + l15;
    const int kb = kk * 32 + l4 * 8;
    bf16x8 v;
#pragma unroll
    for (int i = 0; i < 8; ++i) v[i] = f2bf(W2[(kb + i) * 64 + c]);
    B2[kk] = v;
  }
  const float b2v = b2[w * 16 + l15];

  // m1 / i1 tables to LDS (2 KB)
  reinterpret_cast<float*>(lds + 32768)[tid] = ws[WS_M1 + tid];
  reinterpret_cast<float*>(lds + 33792)[tid] = ws[WS_I1 + tid];

  float s2A = 0.f, q2A = 0.f;
  const int nTiles = E >> 6;

  for (int t = blockIdx.x; t < nTiles; t += gridDim.x) {
    __syncthreads(); // prev iter's img/bounce readers done (and m1/i1 visible, 1st iter)

    // ---- stage h1 image tile: linear async copy (image is pre-swizzled)
    {
      const char* src = h1img + (size_t)t * 32768 + w * 8192 + lane * 16;
      char* dst = lds + w * 8192;
#pragma unroll
      for (int r = 0; r < 8; ++r)
        ASYNC_COPY16(src + r * 1024, dst + r * 1024);
    }
    __syncthreads(); // drains vmcnt -> img ready

    // ---- GEMM2 with norm1+ReLU fused into A-fragment load
    f32x4 acc2[4];
#pragma unroll
    for (int mi = 0; mi < 4; ++mi) acc2[mi] = f32x4{0.f, 0.f, 0.f, 0.f};
#pragma unroll
    for (int kk = 0; kk < 8; ++kk) {
      const int cb = (kk * 32 + l4 * 8) * 4; // byte offset into the f32 tables
      const float4 m1a = *reinterpret_cast<const float4*>(lds + 32768 + cb);
      const float4 m1b = *reinterpret_cast<const float4*>(lds + 32768 + cb + 16);
      const float4 i1a = *reinterpret_cast<const float4*>(lds + 33792 + cb);
      const float4 i1b = *reinterpret_cast<const float4*>(lds + 33792 + cb + 16);
      const float mv[8] = {m1a.x, m1a.y, m1a.z, m1a.w, m1b.x, m1b.y, m1b.z, m1b.w};
      const float iv[8] = {i1a.x, i1a.y, i1a.z, i1a.w, i1b.x, i1b.y, i1b.z, i1b.w};
#pragma unroll
      for (int mi = 0; mi < 4; ++mi) {
        const int row = mi * 16 + l15;
        int byte = row * 512 + kk * 64 + l4 * 16;
        byte ^= (row & 7) << 4;
        const bf16x8 a = *reinterpret_cast<const bf16x8*>(lds + byte);
        bf16x8 an;
#pragma unroll
        for (int i = 0; i < 8; ++i) {
          float v = bf2f((unsigned short)a[i]);
          v = (v - mv[i]) * iv[i];
          an[i] = f2bf(v > 0.f ? v : 0.f);
        }
        acc2[mi] = __builtin_amdgcn_mfma_f32_16x16x32_bf16(an, B2[kk], acc2[mi], 0, 0, 0);
      }
    }
    __syncthreads(); // img reads done before bounce overwrites [0,8192)

    // ---- stats2 + bounce write [64 rows][64 cols] b16, row-rotated banks
#pragma unroll
    for (int mi = 0; mi < 4; ++mi)
#pragma unroll
      for (int r = 0; r < 4; ++r) {
        const int row = mi * 16 + l4 * 4 + r;
        const float v = acc2[mi][r] + b2v;
        s2A += v;
        q2A += v * v;
        int byte = row * 128 + (w * 16 + l15) * 2;
        byte ^= ((row >> 2) & 3) << 5;
        *reinterpret_cast<short*>(lds + byte) = f2bf(v);
      }
    __syncthreads();

    // ---- bounce read -> h2 global, full 128B lines, nontemporal (no RMW fetch)
    {
      const int row = tid >> 2, ch = tid & 3;
      const int rb = row * 128 + ((ch * 32) ^ (((row >> 2) & 3) << 5));
      const bf16x8 v0 = *reinterpret_cast<const bf16x8*>(lds + rb);
      const bf16x8 v1 = *reinterpret_cast<const bf16x8*>(lds + rb + 16);
      char* dstG = (char*)h2s + (size_t)t * 8192 + row * 128 + ch * 32;
      __builtin_nontemporal_store(v0, reinterpret_cast<bf16x8*>(dstG));
      __builtin_nontemporal_store(v1, reinterpret_cast<bf16x8*>(dstG + 16));
    }
  }

  // ---- flush stats2
  {
    float s = s2A, q = q2A;
    s += __shfl_xor(s, 16); s += __shfl_xor(s, 32);
    q += __shfl_xor(q, 16); q += __shfl_xor(q, 32);
    if (lane < 16) {
      atomicAdd(&ws[WS_SUM2 + w * 16 + lane], s);
      atomicAdd(&ws[WS_SQ2 + w * 16 + lane], q);
    }
  }
}

// ============ FALLBACK (round-3 structure, spill-free bounds) ============
// MODE 0: GEMM1 -> stats1.  MODE 1: +norm+GEMM2 -> stats2 (+h2 store).
// MODE 2: full recompute -> out.
template <int MODE>
__global__ __launch_bounds__(256, 2) void fused_pass(
    const float* __restrict__ emb, const int* __restrict__ ei,
    const float* __restrict__ W1, const float* __restrict__ b1,
    const float* __restrict__ W2, const float* __restrict__ b2,
    const float* __restrict__ W3, const float* __restrict__ b3,
    float* __restrict__ ws, unsigned short* __restrict__ h2s,
    float* __restrict__ out, int E, int storeH2) {
  extern __shared__ __align__(16) char lds[];
  const int tid = threadIdx.x;
  const int lane = tid & 63;
  const int w = tid >> 6;
  const int l15 = lane & 15;
  const int l4 = lane >> 4;

  bf16x8 B1[4][4];
#pragma unroll
  for (int ni = 0; ni < 4; ++ni)
#pragma unroll
    for (int kk = 0; kk < 4; ++kk) {
      const int c = w * 64 + ni * 16 + l15;
      const int kb = kk * 32 + l4 * 8;
      bf16x8 v;
#pragma unroll
      for (int i = 0; i < 8; ++i) v[i] = f2bf(W1[(kb + i) * 256 + c]);
      B1[ni][kk] = v;
    }
  float b1v[4], m1v[4] = {0, 0, 0, 0}, i1v[4] = {0, 0, 0, 0};
#pragma unroll
  for (int ni = 0; ni < 4; ++ni) {
    const int c = w * 64 + ni * 16 + l15;
    b1v[ni] = b1[c];
    if (MODE >= 1) { m1v[ni] = ws[WS_M1 + c]; i1v[ni] = ws[WS_I1 + c]; }
  }
  bf16x8 B2[8];
  float b2v = 0.f, m2v = 0.f, i2v = 0.f, w3v = 0.f;
  if (MODE >= 1) {
#pragma unroll
    for (int kk = 0; kk < 8; ++kk) {
      const int c = w * 16 + l15;
      const int kb = kk * 32 + l4 * 8;
      bf16x8 v;
#pragma unroll
      for (int i = 0; i < 8; ++i) v[i] = f2bf(W2[(kb + i) * 64 + c]);
      B2[kk] = v;
    }
    b2v = b2[w * 16 + l15];
    if (MODE == 2) {
      m2v = ws[WS_M2 + w * 16 + l15];
      i2v = ws[WS_I2 + w * 16 + l15];
      w3v = W3[w * 16 + l15];
    }
  }

  float sAcc[4] = {0, 0, 0, 0}, qAcc[4] = {0, 0, 0, 0};
  float s2A = 0.f, q2A = 0.f;

  const int nTiles = E >> 6;
  for (int t = blockIdx.x; t < nTiles; t += gridDim.x) {
    const int e0 = t << 6;
    __syncthreads();

    {
      const int e = tid >> 2, q = tid & 3;
      const int nidx = (q < 2) ? ei[e0 + e] : ei[E + e0 + e];
      const float* src = emb + (long)nidx * 64 + (q & 1) * 32;
#pragma unroll
      for (int jj = 0; jj < 4; ++jj) {
        float4 fa = *reinterpret_cast<const float4*>(src + jj * 8);
        float4 fb = *reinterpret_cast<const float4*>(src + jj * 8 + 4);
        bf16x8 p;
        p[0] = f2bf(fa.x); p[1] = f2bf(fa.y); p[2] = f2bf(fa.z); p[3] = f2bf(fa.w);
        p[4] = f2bf(fb.x); p[5] = f2bf(fb.y); p[6] = f2bf(fb.z); p[7] = f2bf(fb.w);
        int byte = e * 256 + q * 64 + jj * 16;
        byte ^= (e & 7) << 4;
        *reinterpret_cast<bf16x8*>(lds + byte) = p;
      }
      if (MODE == 2) {
        if (tid < 64) reinterpret_cast<float*>(lds + 49152)[tid] = 0.f;
      }
    }
    __syncthreads();

    f32x4 acc[4][4];
#pragma unroll
    for (int mi = 0; mi < 4; ++mi)
#pragma unroll
      for (int ni = 0; ni < 4; ++ni) acc[mi][ni] = f32x4{0.f, 0.f, 0.f, 0.f};
#pragma unroll
    for (int kk = 0; kk < 4; ++kk) {
      bf16x8 af[4];
#pragma unroll
      for (int mi = 0; mi < 4; ++mi) {
        const int row = mi * 16 + l15;
        int byte = row * 256 + kk * 64 + l4 * 16;
        byte ^= (row & 7) << 4;
        af[mi] = *reinterpret_cast<const bf16x8*>(lds + byte);
      }
#pragma unroll
      for (int ni = 0; ni < 4; ++ni)
#pragma unroll
        for (int mi = 0; mi < 4; ++mi)
          acc[mi][ni] = __builtin_amdgcn_mfma_f32_16x16x32_bf16(af[mi], B1[ni][kk], acc[mi][ni], 0, 0, 0);
    }

    if (MODE == 0) {
#pragma unroll
      for (int mi = 0; mi < 4; ++mi)
#pragma unroll
        for (int ni = 0; ni < 4; ++ni)
#pragma unroll
          for (int r = 0; r < 4; ++r) {
            const float v = acc[mi][ni][r] + b1v[ni];
            sAcc[ni] += v;
            qAcc[ni] += v * v;
          }
    } else {
      char* g = lds + 16384;
#pragma unroll
      for (int mi = 0; mi < 4; ++mi)
#pragma unroll
        for (int ni = 0; ni < 4; ++ni) {
          const int c = w * 64 + ni * 16 + l15;
#pragma unroll
          for (int r = 0; r < 4; ++r) {
            const int row = mi * 16 + l4 * 4 + r;
            float v = (acc[mi][ni][r] + b1v[ni] - m1v[ni]) * i1v[ni];
            v = v > 0.f ? v : 0.f;
            int byte = row * 512 + c * 2;
            byte ^= (row & 7) << 4;
            *reinterpret_cast<short*>(g + byte) = f2bf(v);
          }
        }
      __syncthreads();

      f32x4 acc2[4];
#pragma unroll
      for (int mi = 0; mi < 4; ++mi) acc2[mi] = f32x4{0.f, 0.f, 0.f, 0.f};
#pragma unroll
      for (int kk = 0; kk < 8; ++kk) {
#pragma unroll
        for (int mi = 0; mi < 4; ++mi) {
          const int row = mi * 16 + l15;
          int byte = row * 512 + kk * 64 + l4 * 16;
          byte ^= (row & 7) << 4;
          const bf16x8 a2 = *reinterpret_cast<const bf16x8*>(g + byte);
          acc2[mi] = __builtin_amdgcn_mfma_f32_16x16x32_bf16(a2, B2[kk], acc2[mi], 0, 0, 0);
        }
      }

      if (MODE == 1) {
#pragma unroll
        for (int mi = 0; mi < 4; ++mi)
#pragma unroll
          for (int r = 0; r < 4; ++r) {
            const float v = acc2[mi][r] + b2v;
            s2A += v;
            q2A += v * v;
            if (storeH2) {
              const int row = e0 + mi * 16 + l4 * 4 + r;
              h2s[(size_t)row * 64 + w * 16 + l15] = (unsigned short)f2bf(v);
            }
          }
      } else {
        float* outp = reinterpret_cast<float*>(lds + 49152);
#pragma unroll
        for (int mi = 0; mi < 4; ++mi)
#pragma unroll
          for (int r = 0; r < 4; ++r) {
            const float v = acc2[mi][r] + b2v;
            float z = (v - m2v) * i2v;
            z = z > 0.f ? z : 0.f;
            float pv = z * w3v;
            pv += __shfl_xor(pv, 1);
            pv += __shfl_xor(pv, 2);
            pv += __shfl_xor(pv, 4);
            pv += __shfl_xor(pv, 8);
            if (l15 == 0) atomicAdd(&outp[mi * 16 + l4 * 4 + r], pv);
          }
        __syncthreads();
        if (tid < 64) out[e0 + tid] = outp[tid] + b3[0];
      }
    }
  }

  if (MODE == 0) {
#pragma unroll
    for (int ni = 0; ni < 4; ++ni) {
      float s = sAcc[ni], q = qAcc[ni];
      s += __shfl_xor(s, 16); s += __shfl_xor(s, 32);
      q += __shfl_xor(q, 16); q += __shfl_xor(q, 32);
      if (lane < 16) {
        atomicAdd(&ws[WS_SUM1 + w * 64 + ni * 16 + lane], s);
        atomicAdd(&ws[WS_SQ1 + w * 64 + ni * 16 + lane], q);
      }
    }
  }
  if (MODE == 1) {
    float s = s2A, q = q2A;
    s += __shfl_xor(s, 16); s += __shfl_xor(s, 32);
    q += __shfl_xor(q, 16); q += __shfl_xor(q, 32);
    if (lane < 16) {
      atomicAdd(&ws[WS_SUM2 + w * 16 + lane], s);
      atomicAdd(&ws[WS_SQ2 + w * 16 + lane], q);
    }
  }
}

// epilogue from stored h2 (bf16): norm2 + relu + dot(W3) + b3
__global__ void k_out(const unsigned short* __restrict__ h2s, const float* __restrict__ ws,
                      const float* __restrict__ W3, const float* __restrict__ b3,
                      float* __restrict__ out, int E) {
  __shared__ float sm[64], si[64], sw[64];
  const int tid = threadIdx.x;
  if (tid < 64) {
    sm[tid] = ws[WS_M2 + tid];
    si[tid] = ws[WS_I2 + tid];
    sw[tid] = W3[tid];
  }
  __syncthreads();
  const int e = blockIdx.x * 256 + tid;
  if (e >= E) return;
  const unsigned short* rp = h2s + (size_t)e * 64;
  float a = 0.f;
#pragma unroll
  for (int jj = 0; jj < 8; ++jj) {
    const bf16x8 v8 = *reinterpret_cast<const bf16x8*>(rp + jj * 8);
#pragma unroll
    for (int i = 0; i < 8; ++i) {
      const int j = jj * 8 + i;
      const float v = bf2f((unsigned short)v8[i]);
      float z = (v - sm[j]) * si[j];
      z = z > 0.f ? z : 0.f;
      a += z * sw[j];
    }
  }
  out[e] = a + b3[0];
}

extern "C" void kernel_launch(void* const* d_in, const int* in_sizes, int n_in,
                              void* d_out, int out_size, void* d_ws, size_t ws_size,
                              hipStream_t stream) {
  (void)n_in; (void)out_size;
  const float* emb = (const float*)d_in[0];
  const int* ei = (const int*)d_in[1];
  const float* W1 = (const float*)d_in[2];
  const float* b1 = (const float*)d_in[3];
  const float* W2 = (const float*)d_in[4];
  const float* b2 = (const float*)d_in[5];
  const float* W3 = (const float*)d_in[6];
  const float* b3 = (const float*)d_in[7];
  float* out = (float*)d_out;
  float* ws = (float*)d_ws;
  unsigned short* h2s = (unsigned short*)((char*)d_ws + H2S_BYTE_OFF);

  const int E = in_sizes[1] / 2;
  const size_t h2bytes = (size_t)E * 64 * 2;    // 102.4 MB
  const size_t h1bytes = (size_t)E * 256 * 2;   // 409.6 MB
  char* h1img = (char*)d_ws + H2S_BYTE_OFF + h2bytes;
  const int storeH2 = (ws_size >= (size_t)H2S_BYTE_OFF + h2bytes) ? 1 : 0;
  const int storeH1 = (ws_size >= (size_t)H2S_BYTE_OFF + h2bytes + h1bytes) ? 1 : 0;
  const float invE = 1.0f / (float)E;

  k_zero<<<1, 256, 0, stream>>>(ws);
  if (storeH1) {
    // main path: GEMM1 once, pass B is pure streaming
    k_pass_a<<<1024, 256, 49152, stream>>>(emb, ei, W1, b1, ws, h1img, E);
    k_finalize<<<1, 256, 0, stream>>>(ws, 256, WS_SUM1, WS_SQ1, WS_M1, WS_I1, invE);
    k_pass_b<<<2048, 256, 34816, stream>>>(h1img, W2, b2, ws, h2s, E);
    k_finalize<<<1, 256, 0, stream>>>(ws, 64, WS_SUM2, WS_SQ2, WS_M2, WS_I2, invE);
    k_out<<<(E + 255) / 256, 256, 0, stream>>>(h2s, ws, W3, b3, out, E);
  } else {
    // fallback: round-3 structure (spill-free bounds)
    fused_pass<0><<<768, 256, 16384, stream>>>(emb, ei, W1, b1, W2, b2, W3, b3, ws, h2s, out, E, storeH2);
    k_finalize<<<1, 256, 0, stream>>>(ws, 256, WS_SUM1, WS_SQ1, WS_M1, WS_I1, invE);
    fused_pass<1><<<512, 256, 49152, stream>>>(emb, ei, W1, b1, W2, b2, W3, b3, ws, h2s, out, E, storeH2);
    k_finalize<<<1, 256, 0, stream>>>(ws, 64, WS_SUM2, WS_SQ2, WS_M2, WS_I2, invE);
    if (storeH2)
      k_out<<<(E + 255) / 256, 256, 0, stream>>>(h2s, ws, W3, b3, out, E);
    else
      fused_pass<2><<<512, 256, 49408, stream>>>(emb, ei, W1, b1, W2, b2, W3, b3, ws, h2s, out, E, storeH2);
  }
}